// Round 13
// baseline (214.372 us; speedup 1.0000x reference)
//
#include <hip/hip_runtime.h>
#include <hip/hip_fp16.h>

// Problem constants: B=4, N=2048, D=1024, H=16, DH=64.  M = B*N = 8192.

typedef _Float16 half8 __attribute__((ext_vector_type(8)));
typedef _Float16 half4 __attribute__((ext_vector_type(4)));
typedef float f32x4 __attribute__((ext_vector_type(4)));
typedef float f32x16 __attribute__((ext_vector_type(16)));
typedef unsigned int u32x4 __attribute__((ext_vector_type(4)));

#define DEV __device__ __forceinline__
#define MFMA16(a, b, c) __builtin_amdgcn_mfma_f32_16x16x32_f16(a, b, c, 0, 0, 0)
#define MFMA32(a, b, c) __builtin_amdgcn_mfma_f32_32x32x16_f16(a, b, c, 0, 0, 0)

DEV void gload_lds16(const void* g, void* l) {
  __builtin_amdgcn_global_load_lds(
      (const __attribute__((address_space(1))) void*)g,
      (__attribute__((address_space(3))) void*)l, 16, 0, 0);
}

// ---------------- fused cast f32 -> f16 (x + 4 weight matrices) ------------
__global__ __launch_bounds__(256) void cast_all(
    const float* __restrict__ x, const float* __restrict__ Wq,
    const float* __restrict__ Wk, const float* __restrict__ Wv,
    const float* __restrict__ Wp, __half* __restrict__ xb,
    __half* __restrict__ wqkv, __half* __restrict__ wpb) {
  int i = blockIdx.x * 256 + threadIdx.x;
  const float* s;
  __half* d;
  int j;
  if (i < 1048576) {
    s = x; d = xb; j = i;
  } else {
    int k = i - 1048576;
    int sel = k >> 17;
    j = k & 131071;
    s = (sel == 0) ? Wq : (sel == 1) ? Wk : (sel == 2) ? Wv : Wp;
    d = (sel == 3) ? wpb : (wqkv + sel * 1048576);
  }
  const float4* sp = (const float4*)s + (size_t)j * 2;
  float4 a = sp[0], b = sp[1];
  half8 h;
  h[0] = (_Float16)a.x; h[1] = (_Float16)a.y; h[2] = (_Float16)a.z; h[3] = (_Float16)a.w;
  h[4] = (_Float16)b.x; h[5] = (_Float16)b.y; h[6] = (_Float16)b.z; h[7] = (_Float16)b.w;
  *((half8*)d + j) = h;
}

// ---------------- 128x128 GEMM, NT (both operands K-contiguous), K=1024 ----
// MODE 0: QKV epilogue (q scaled 8*log2e, V written transposed to vt).
// MODE 1: proj epilogue -> f32 out + bias.
// T2 LDS swizzle (r12: killed the 18.9M-cycle bank conflict; gemm dropped
// out of the top-5 dispatches).  Natural grid mapping.
template <int MODE>
__global__ __launch_bounds__(256) void gemm128(
    const __half* __restrict__ A, const __half* __restrict__ Bm,
    const float* __restrict__ b0, const float* __restrict__ b1,
    const float* __restrict__ b2, __half* __restrict__ oh,
    __half* __restrict__ vtp, float* __restrict__ of) {
  const int m0 = blockIdx.y * 128;
  const int n0 = blockIdx.x * 128;
  const int tid = threadIdx.x;
  const int w = tid >> 6, lane = tid & 63;
  const int lr = lane & 15, lq = lane >> 4;
  const int wr = w >> 1, wc = w & 1;

  __shared__ alignas(16) __half As[128 * 64];
  __shared__ alignas(16) __half Bs[128 * 64];

  f32x4 acc[4][4] = {};

  const int arow = lane >> 3;
  // pre-swizzled source column: LDS ends up holding
  // byte = (row*128 + col*2) ^ ((row&7)<<4)  with a LINEAR gload_lds dest
  const int acol = ((lane & 7) ^ arow) * 8;
  const __half* Agp = A + ((size_t)m0 + w * 32 + arow) * 1024 + acol;
  const __half* Bgp = Bm + ((size_t)n0 + w * 32 + arow) * 1024 + acol;

  for (int kt = 0; kt < 16; ++kt) {
#pragma unroll
    for (int j = 0; j < 4; ++j) {
      gload_lds16(Agp + j * 8192 + kt * 64, As + (w * 4 + j) * 512);
      gload_lds16(Bgp + j * 8192 + kt * 64, Bs + (w * 4 + j) * 512);
    }
    __syncthreads();
#pragma unroll
    for (int s = 0; s < 2; ++s) {
      half8 af[4], bf[4];
#pragma unroll
      for (int i = 0; i < 4; ++i) {
        int rowA = wr * 64 + i * 16 + lr;
        int rowB = wc * 64 + i * 16 + lr;
        af[i] = *(const half8*)((const char*)As +
                                ((rowA * 128 + s * 64 + lq * 16) ^ ((rowA & 7) << 4)));
        bf[i] = *(const half8*)((const char*)Bs +
                                ((rowB * 128 + s * 64 + lq * 16) ^ ((rowB & 7) << 4)));
      }
#pragma unroll
      for (int mi = 0; mi < 4; ++mi)
#pragma unroll
        for (int ni = 0; ni < 4; ++ni)
          acc[mi][ni] = MFMA16(af[mi], bf[ni], acc[mi][ni]);
    }
    __syncthreads();
  }

  if (MODE == 0) {
#pragma unroll
    for (int ni = 0; ni < 4; ++ni) {
      int col = n0 + wc * 64 + ni * 16 + lr;
      int t = col >> 10, e = col & 1023;
      const float* bb = (t == 0) ? b0 : ((t == 1) ? b1 : b2);
      float bias = bb[e];
      int hh = e >> 6, dh = e & 63;
      if (t == 2) {
#pragma unroll
        for (int mi = 0; mi < 4; ++mi) {
          int row = m0 + wr * 64 + mi * 16 + lq * 4;
          int b_ = row >> 11, n = row & 2047;
          half4 h;
#pragma unroll
          for (int r = 0; r < 4; ++r) h[r] = (_Float16)(acc[mi][ni][r] + bias);
          *(half4*)(vtp + (size_t)(b_ * 16 + hh) * 131072 + (size_t)dh * 2048 + n) = h;
        }
      } else {
        float scale = (t == 0) ? 11.541560327111707f : 1.0f;
        __half* base = oh + (size_t)t * 8388608 + dh;
#pragma unroll
        for (int mi = 0; mi < 4; ++mi)
#pragma unroll
          for (int r = 0; r < 4; ++r) {
            int row = m0 + wr * 64 + mi * 16 + lq * 4 + r;
            int b_ = row >> 11, n = row & 2047;
            float v = (acc[mi][ni][r] + bias) * scale;
            base[(((size_t)(b_ * 16 + hh) * 2048 + n) * 64)] = __float2half(v);
          }
      }
    }
  } else {
#pragma unroll
    for (int ni = 0; ni < 4; ++ni) {
      int col = n0 + wc * 64 + ni * 16 + lr;
      float bias = b0[col];
#pragma unroll
      for (int mi = 0; mi < 4; ++mi)
#pragma unroll
        for (int r = 0; r < 4; ++r) {
          int row = m0 + wr * 64 + mi * 16 + lq * 4 + r;
          of[(size_t)row * 1024 + col] = acc[mi][ni][r] + bias;
        }
    }
  }
}

// ---------------- causal flash attention, 32x32 swapped-operand ------------
// Q,K: [bh][2048][64] f16 (Q pre-scaled by 8*log2e).  Vt: [bh][64][2048] f16.
// O: [b][n][h*64+dh] f16.
// 256 thr = 4 waves; wave w owns 32 q rows (q = q0 + w*32 + (lane&31)).
// S^T = MFMA32(K_frag, Q_frag): lane pair (c, c+32) co-owns query c; 16 keys
// per lane in regs (key = (r&3)+8*(r>>2)+4*hi, m74/m101 layout, VERIFIED in
// r3/r4 passing runs).  Softmax needs ONE cross-lane op (xor 32); P is
// packed in-register and exchanged with 8 shfl_xor(32) per 32-key chunk --
// vs the dual-16x16 form's 32 bpermute+selects (r12's LDS-port bottleneck).
// Single accumulator set (~115 live regs) under a 170-reg cap: r3/r4's
// failure was 2 acc sets at a 128 cap (spill) -- eliminated here.
// O^T epilogue goes through a per-wave LDS transpose (r3's verified idx
// math) after a block barrier, then coalesced u32x4 stores.
// Grid 1024: bh = wg&63 (XCD affinity), qt = 15-(wg>>6) longest-first.
// Staging: r12's shell verbatim (dbuf, pre-swizzled source, vmcnt(4)).
__global__ __launch_bounds__(256, 3) void attn32(const __half* __restrict__ Q,
                                                 const __half* __restrict__ K,
                                                 const __half* __restrict__ Vt,
                                                 __half* __restrict__ O) {
  const int wg = blockIdx.x;
  const int bh = wg & 63;
  const int qt = 15 - (wg >> 6);
  const int b = bh >> 4, h = bh & 15;
  const int tid = threadIdx.x;
  const int w = tid >> 6, lane = tid & 63;
  const int c = lane & 31, hi = lane >> 5;

  __shared__ alignas(16) char smem[32768];
  __half* KsH = (__half*)smem;             // 2 bufs x 4096 halves
  __half* VsH = (__half*)(smem + 16384);   // 2 bufs x 4096 halves

  const __half* Kb = K + (size_t)bh * 131072;
  const __half* Vb = Vt + (size_t)bh * 131072;

  // staging: linear LDS dest; source column pre-swizzled so LDS holds
  // byte = (r*128 + col*2) ^ ((r&7)<<4)
  const int srow0 = tid >> 3;
  const int srow1 = srow0 + 32;
  const int scol = ((tid & 7) ^ (srow0 & 7)) * 8;

#define STAGE(t, buf)                                                          \
  do {                                                                         \
    gload_lds16(Kb + (size_t)((t)*64 + srow0) * 64 + scol,                     \
                KsH + (buf)*4096 + tid * 8);                                   \
    gload_lds16(Kb + (size_t)((t)*64 + srow1) * 64 + scol,                     \
                KsH + (buf)*4096 + 2048 + tid * 8);                            \
    gload_lds16(Vb + (size_t)srow0 * 2048 + (t)*64 + scol,                     \
                VsH + (buf)*4096 + tid * 8);                                   \
    gload_lds16(Vb + (size_t)srow1 * 2048 + (t)*64 + scol,                     \
                VsH + (buf)*4096 + 2048 + tid * 8);                            \
  } while (0)

  const int q0 = qt * 128;
  const int ktend = 2 * qt + 2;
  const int rmin = q0 + w * 32;
  const int myq = rmin + c;

  // Q B-fragments: B[col=q=c][k = ksl*16 + hi*8 + j]  (r3-verified)
  const __half* Qp = Q + ((size_t)bh * 2048 + myq) * 64;
  half8 qf[4];
#pragma unroll
  for (int i = 0; i < 4; ++i) qf[i] = *(const half8*)(Qp + i * 16 + hi * 8);

  f32x16 accA = {0,0,0,0,0,0,0,0,0,0,0,0,0,0,0,0};  // O^T, dh 0-31
  f32x16 accB = {0,0,0,0,0,0,0,0,0,0,0,0,0,0,0,0};  // O^T, dh 32-63
  float m = -INFINITY, lp = 0.f;

  STAGE(0, 0);
  asm volatile("" ::: "memory");

  // exp2 + pack + hi/lo exchange + PV for one 32-key chunk (r4-verified)
  auto chunk = [&](f32x16& sv, const int kc, const char* Vcl) {
    float l0 = 0.f, l1 = 0.f, l2 = 0.f, l3 = 0.f;
#pragma unroll
    for (int r = 0; r < 16; r += 4) {
      sv[r] = __builtin_amdgcn_exp2f(sv[r] - m);
      sv[r + 1] = __builtin_amdgcn_exp2f(sv[r + 1] - m);
      sv[r + 2] = __builtin_amdgcn_exp2f(sv[r + 2] - m);
      sv[r + 3] = __builtin_amdgcn_exp2f(sv[r + 3] - m);
      l0 += sv[r]; l1 += sv[r + 1]; l2 += sv[r + 2]; l3 += sv[r + 3];
    }
    lp += (l0 + l1) + (l2 + l3);
    unsigned pk[8], xk[8];
#pragma unroll
    for (int i = 0; i < 8; ++i) {
      __half2 h2 = __floats2half2_rn(sv[2 * i], sv[2 * i + 1]);
      pk[i] = *(unsigned*)&h2;
      xk[i] = __shfl_xor(pk[i], 32);
    }
#pragma unroll
    for (int ksl = 0; ksl < 2; ++ksl) {
      // B-frag needs P[key = ks*16 + hi*8 + j][q=c]
      const int i0 = 2 * hi + 4 * ksl;
      u32x4 fu;
      fu[0] = hi ? xk[i0] : pk[i0];
      fu[1] = hi ? xk[i0 + 1] : pk[i0 + 1];
      fu[2] = hi ? pk[i0] : xk[i0];
      fu[3] = hi ? pk[i0 + 1] : xk[i0 + 1];
      half8 pf = *(half8*)&fu;
      const int ks = kc * 2 + ksl;
      half8 va = *(const half8*)(Vcl + ((c * 128 + ks * 32 + hi * 16) ^ ((c & 7) << 4)));
      half8 vb = *(const half8*)(Vcl + (((c + 32) * 128 + ks * 32 + hi * 16) ^ ((c & 7) << 4)));
      __builtin_amdgcn_s_setprio(1);
      accA = MFMA32(va, pf, accA);
      accB = MFMA32(vb, pf, accB);
      __builtin_amdgcn_s_setprio(0);
    }
  };

  for (int kt = 0; kt < ktend; ++kt) {
    const int cur = kt & 1;
    const int k0 = kt * 64;
    if (kt + 1 < ktend) {
      STAGE(kt + 1, cur ^ 1);
      asm volatile("s_waitcnt vmcnt(4)" ::: "memory");
    } else {
      asm volatile("s_waitcnt vmcnt(0)" ::: "memory");
    }
    __builtin_amdgcn_s_barrier();
    asm volatile("" ::: "memory");

    const char* Kc = smem + cur * 8192;
    const char* Vc = smem + 16384 + cur * 8192;
    if (k0 <= rmin + 31) {
      // --- S^T = K Q^T (keys 0-31 -> sA, 32-63 -> sB)  (r3-verified)
      f32x16 sA = {0,0,0,0,0,0,0,0,0,0,0,0,0,0,0,0};
      f32x16 sB = {0,0,0,0,0,0,0,0,0,0,0,0,0,0,0,0};
      __builtin_amdgcn_s_setprio(1);
#pragma unroll
      for (int ksl = 0; ksl < 4; ++ksl) {
        half8 ka = *(const half8*)(Kc + ((c * 128 + ksl * 32 + hi * 16) ^ ((c & 7) << 4)));
        half8 kb = *(const half8*)(Kc + (((c + 32) * 128 + ksl * 32 + hi * 16) ^ ((c & 7) << 4)));
        sA = MFMA32(ka, qf[ksl], sA);
        sB = MFMA32(kb, qf[ksl], sB);
      }
      __builtin_amdgcn_s_setprio(0);

      // --- causal mask: key(r,hi) = (r&3) + 8*(r>>2) + 4*hi  (r3-verified)
      if (k0 + 63 > rmin) {
#pragma unroll
        for (int r = 0; r < 16; ++r) {
          int key = k0 + (r & 3) + 8 * (r >> 2) + 4 * hi;
          if (key > myq) sA[r] = -INFINITY;
          if (key + 32 > myq) sB[r] = -INFINITY;
        }
      }

      // --- row max: in-reg tree + ONE cross-lane exchange
      float rm = -INFINITY;
#pragma unroll
      for (int r = 0; r < 16; ++r) rm = fmaxf(rm, fmaxf(sA[r], sB[r]));
      rm = fmaxf(rm, __shfl_xor(rm, 32));

      // defer-max (T13)
      if (__any(rm > m + 8.f)) {
        float mn = fmaxf(m, rm);
        float al = __builtin_amdgcn_exp2f(m - mn);
        m = mn;
        lp *= al;
#pragma unroll
        for (int r = 0; r < 16; ++r) { accA[r] *= al; accB[r] *= al; }
      }

      chunk(sA, 0, Vc);
      chunk(sB, 1, Vc);
    }
    asm volatile("s_waitcnt lgkmcnt(0)" ::: "memory");
    __builtin_amdgcn_s_barrier();
    asm volatile("" ::: "memory");
  }

  // ---- epilogue: normalize, per-wave LDS transpose, coalesced O write ----
  float lt = lp + __shfl_xor(lp, 32);
  float linv = 1.0f / lt;
  __syncthreads();  // all compute done; smem reused as transpose scratch
  unsigned* tr = (unsigned*)(smem + w * 4608);  // [32 q][36 u32 cols]
#pragma unroll
  for (int dt = 0; dt < 2; ++dt)
#pragma unroll
    for (int i = 0; i < 8; ++i) {
      float v0 = (dt ? accB[2 * i] : accA[2 * i]) * linv;
      float v1 = (dt ? accB[2 * i + 1] : accA[2 * i + 1]) * linv;
      __half2 h2 = __floats2half2_rn(v0, v1);
      // dh pair base = 2(i&1) + 8(i>>1) + 4hi + 32dt  -> u32 col (r3-verified)
      int idx = (i & 1) + 4 * (i >> 1) + 2 * hi + 16 * dt;
      tr[c * 36 + idx] = *(unsigned*)&h2;
    }
  asm volatile("s_waitcnt lgkmcnt(0)" ::: "memory");
  __builtin_amdgcn_sched_barrier(0);
  const int rq = lane >> 1, ch = lane & 1;
  __half* Op = O + ((size_t)b * 2048 + rmin + rq) * 1024 + h * 64 + ch * 32;
#pragma unroll
  for (int ii = 0; ii < 4; ++ii) {
    u32x4 u = *(const u32x4*)(tr + rq * 36 + ch * 16 + 4 * ii);
    *(u32x4*)(Op + ii * 8) = u;
  }
#undef STAGE
}

// ---------------- launch ---------------------------------------------------
extern "C" void kernel_launch(void* const* d_in, const int* in_sizes, int n_in,
                              void* d_out, int out_size, void* d_ws,
                              size_t ws_size, hipStream_t stream) {
  const float* x = (const float*)d_in[0];
  const float* Wq = (const float*)d_in[1];
  const float* bq = (const float*)d_in[2];
  const float* Wk = (const float*)d_in[3];
  const float* bk = (const float*)d_in[4];
  const float* Wv = (const float*)d_in[5];
  const float* bv = (const float*)d_in[6];
  const float* Wp = (const float*)d_in[7];
  const float* bp = (const float*)d_in[8];

  // workspace layout (bytes)
  char* ws = (char*)d_ws;
  const size_t XB = 0;                       // 16777216
  const size_t WQKV = XB + 16777216;         // 6291456
  const size_t WPB = WQKV + 6291456;         // 2097152
  const size_t QKV = WPB + 2097152;          // 50331648 (v slot unused)
  const size_t VT = QKV + 50331648;          // 16777216
  const size_t OB = VT + 16777216;           // 16777216  (~109 MiB)

  __half* xb = (__half*)(ws + XB);
  __half* wqkv = (__half*)(ws + WQKV);
  __half* wpb = (__half*)(ws + WPB);
  __half* qkv = (__half*)(ws + QKV);
  __half* vt = (__half*)(ws + VT);
  __half* ob = (__half*)(ws + OB);

  // fused cast: x + Wq + Wk + Wv + Wp (1572864 half8 units)
  cast_all<<<6144, 256, 0, stream>>>(x, Wq, Wk, Wv, Wp, xb, wqkv, wpb);

  // QKV: M=8192, N=3072 (V written transposed into vt; T2-swizzled LDS)
  gemm128<0><<<dim3(24, 64), 256, 0, stream>>>(xb, wqkv, bq, bk, bv, qkv, vt,
                                               nullptr);
  // attention (1024 blocks, 4 waves, 32x32 swapped-operand, longest-first)
  attn32<<<dim3(1024), 256, 0, stream>>>(qkv, qkv + 8388608, vt, ob);
  // proj: M=8192, N=1024, f32 out + bias (T2-swizzled LDS)
  gemm128<1><<<dim3(8, 64), 256, 0, stream>>>(ob, wpb, bp, nullptr, nullptr,
                                              nullptr, nullptr, (float*)d_out);
}